// Round 1
// baseline (1762.140 us; speedup 1.0000x reference)
//
#include <hip/hip_runtime.h>
#include <math.h>

#define HEADS 3
#define CDIM 64
#define FDIM 256
#define HC 192      // HEADS*CDIM
#define HIDDIM 128
#define NEG 0.2f

__device__ __forceinline__ void atomicMaxF(float* addr, float val) {
    // works for mixed signs; init bit pattern 0xFFFFFFFF (or -inf) is fine
    if (val >= 0.f) atomicMax((int*)addr, __float_as_int(val));
    else            atomicMin((unsigned int*)addr, __float_as_uint(val));
}

// C[M,N] = A[M,K] @ B[K,N];  requires K%32==0, N%64==0. Row guards on M.
__global__ __launch_bounds__(256) void gemm_tile(const float* __restrict__ A,
                                                 const float* __restrict__ B,
                                                 float* __restrict__ C,
                                                 int M, int K, int N) {
    __shared__ __align__(16) float AsT[32][68];  // [k][row], padded stride 68 (16B aligned rows)
    __shared__ __align__(16) float Bs[32][68];   // [k][col]
    const int tid = threadIdx.x;
    const int tx = tid & 15, ty = tid >> 4;
    const int row0 = blockIdx.x * 64, col0 = blockIdx.y * 64;
    float acc[4][4] = {};
    for (int k0 = 0; k0 < K; k0 += 32) {
        // load A tile 64 rows x 32 k  (transposed into AsT)
        #pragma unroll
        for (int p = 0; p < 2; ++p) {
            int rr = (tid >> 3) + p * 32;
            int k4 = (tid & 7) * 4;
            int gr = row0 + rr;
            float4 v = make_float4(0.f, 0.f, 0.f, 0.f);
            if (gr < M) v = *(const float4*)(A + (size_t)gr * K + k0 + k4);
            AsT[k4 + 0][rr] = v.x; AsT[k4 + 1][rr] = v.y;
            AsT[k4 + 2][rr] = v.z; AsT[k4 + 3][rr] = v.w;
        }
        // load B tile 32 k x 64 cols
        #pragma unroll
        for (int p = 0; p < 2; ++p) {
            int kr = (tid >> 4) + p * 16;
            int c4 = (tid & 15) * 4;
            float4 v = *(const float4*)(B + (size_t)(k0 + kr) * N + col0 + c4);
            Bs[kr][c4 + 0] = v.x; Bs[kr][c4 + 1] = v.y;
            Bs[kr][c4 + 2] = v.z; Bs[kr][c4 + 3] = v.w;
        }
        __syncthreads();
        #pragma unroll
        for (int kk = 0; kk < 32; ++kk) {
            float4 a4 = *(const float4*)&AsT[kk][ty * 4];
            float4 b4 = *(const float4*)&Bs[kk][tx * 4];
            float av[4] = {a4.x, a4.y, a4.z, a4.w};
            float bv[4] = {b4.x, b4.y, b4.z, b4.w};
            #pragma unroll
            for (int i = 0; i < 4; ++i)
                #pragma unroll
                for (int j = 0; j < 4; ++j)
                    acc[i][j] = fmaf(av[i], bv[j], acc[i][j]);
        }
        __syncthreads();
    }
    #pragma unroll
    for (int i = 0; i < 4; ++i) {
        int gr = row0 + ty * 4 + i;
        if (gr < M) {
            float4 v = make_float4(acc[i][0], acc[i][1], acc[i][2], acc[i][3]);
            *(float4*)(C + (size_t)gr * N + col0 + tx * 4) = v;
        }
    }
}

// one wave per node: s_src[n,h] = <h[n,h,:], a_src[h,:]>, same for dst
__global__ __launch_bounds__(256) void attn_scores(const float* __restrict__ Hm,
                                                   const float* __restrict__ a_src,
                                                   const float* __restrict__ a_dst,
                                                   float* __restrict__ s_src,
                                                   float* __restrict__ s_dst, int N) {
    int wave = (int)((blockIdx.x * (size_t)blockDim.x + threadIdx.x) >> 6);
    int lane = threadIdx.x & 63;
    if (wave >= N) return;
    #pragma unroll
    for (int head = 0; head < HEADS; ++head) {
        float v = Hm[(size_t)wave * HC + head * CDIM + lane];
        float ps = v * a_src[head * CDIM + lane];
        float pd = v * a_dst[head * CDIM + lane];
        #pragma unroll
        for (int off = 32; off; off >>= 1) {
            ps += __shfl_down(ps, off);
            pd += __shfl_down(pd, off);
        }
        if (lane == 0) {
            s_src[wave * HEADS + head] = ps;
            s_dst[wave * HEADS + head] = pd;
        }
    }
}

// thread per (edge,head): e = leaky_relu(s_src[src]+s_dst[dst]); atomic max into m[dst]
__global__ __launch_bounds__(256) void edge_pass1(const int* __restrict__ ei,
                                                  const float* __restrict__ s_src,
                                                  const float* __restrict__ s_dst,
                                                  float* __restrict__ e_buf,
                                                  float* __restrict__ mbuf,
                                                  int E, int Etot) {
    int idx = blockIdx.x * blockDim.x + threadIdx.x;
    if (idx >= Etot * HEADS) return;
    int e = idx / HEADS, h = idx - e * HEADS;
    int src, dst;
    if (e < E) { src = ei[e]; dst = ei[E + e]; } else { src = dst = e - E; }
    float s = s_src[src * HEADS + h] + s_dst[dst * HEADS + h];
    float lr = s >= 0.f ? s : NEG * s;
    e_buf[idx] = lr;
    atomicMaxF(&mbuf[dst * HEADS + h], lr);
}

// thread per (edge,head): p = exp(e - m[dst]); atomic add into denom[dst]
__global__ __launch_bounds__(256) void edge_pass2(const int* __restrict__ ei,
                                                  const float* __restrict__ mbuf,
                                                  float* __restrict__ e_buf,
                                                  float* __restrict__ denom,
                                                  int E, int Etot) {
    int idx = blockIdx.x * blockDim.x + threadIdx.x;
    if (idx >= Etot * HEADS) return;
    int e = idx / HEADS, h = idx - e * HEADS;
    int dst = (e < E) ? ei[E + e] : (e - E);
    float p = expf(e_buf[idx] - mbuf[dst * HEADS + h]);
    e_buf[idx] = p;
    atomicAdd(&denom[dst * HEADS + h], p);
}

// wave per (edge,head): out[dst,h,:] += alpha * h[src,h,:]
__global__ __launch_bounds__(256) void edge_pass3(const int* __restrict__ ei,
                                                  const float* __restrict__ e_buf,
                                                  const float* __restrict__ denom,
                                                  const float* __restrict__ Hm,
                                                  float* __restrict__ outg,
                                                  int E, int Etot) {
    int gid = blockIdx.x * blockDim.x + threadIdx.x;
    int wv = gid >> 6;
    int lane = gid & 63;
    if (wv >= Etot * HEADS) return;
    int e = wv / HEADS, h = wv - e * HEADS;
    int src, dst;
    if (e < E) { src = ei[e]; dst = ei[E + e]; } else { src = dst = e - E; }
    float alpha = e_buf[wv] / (denom[dst * HEADS + h] + 1e-16f);
    float v = alpha * Hm[(size_t)src * HC + h * CDIM + lane];
    atomicAdd(&outg[(size_t)dst * HC + h * CDIM + lane], v);
}

__global__ __launch_bounds__(256) void bias_elu(float* __restrict__ outg,
                                                const float* __restrict__ bias,
                                                int total) {
    int i = blockIdx.x * blockDim.x + threadIdx.x;
    if (i >= total) return;
    int c = i % HC;
    float v = outg[i] + bias[c];
    outg[i] = v > 0.f ? v : expm1f(v);
}

// wave per row: beta = (sum_j gelu(hid[j]+b1[j]) * w2[j] + b2) / 100
__global__ __launch_bounds__(256) void beta_kernel(const float* __restrict__ hid,
                                                   const float* __restrict__ b1,
                                                   const float* __restrict__ w2,
                                                   const float* __restrict__ b2,
                                                   float* __restrict__ beta, int N) {
    int gid = blockIdx.x * blockDim.x + threadIdx.x;
    int row = gid >> 6, lane = gid & 63;
    if (row >= N) return;
    float acc = 0.f;
    #pragma unroll
    for (int half = 0; half < 2; ++half) {
        int j = half * 64 + lane;
        float v = hid[(size_t)row * HIDDIM + j] + b1[j];
        float g = 0.5f * v * (1.f + erff(v * 0.70710678118654752f));
        acc += g * w2[j];
    }
    #pragma unroll
    for (int off = 32; off; off >>= 1) acc += __shfl_down(acc, off);
    if (lane == 0) beta[row] = (acc + b2[0]) * 0.01f;
}

// z[f] = sum_n x[n,f] * beta[n]
__global__ __launch_bounds__(256) void xt_beta(const float* __restrict__ X,
                                               const float* __restrict__ beta,
                                               float* __restrict__ z, int N) {
    int f = threadIdx.x;  // 256
    int nPer = (N + gridDim.x - 1) / gridDim.x;
    int n0 = blockIdx.x * nPer;
    int n1 = min(n0 + nPer, N);
    float acc = 0.f;
    for (int n = n0; n < n1; ++n)
        acc = fmaf(X[(size_t)n * FDIM + f], beta[n], acc);
    atomicAdd(&z[f], acc);
}

__global__ void final_sigmoid(const float* __restrict__ zst,
                              const float* __restrict__ zsc,
                              float* __restrict__ out) {
    int f = threadIdx.x;
    float v = zsc[f] + 0.5f * zst[f];
    out[f] = 1.f / (1.f + expf(-v));
}

extern "C" void kernel_launch(void* const* d_in, const int* in_sizes, int n_in,
                              void* d_out, int out_size, void* d_ws, size_t ws_size,
                              hipStream_t stream) {
    const float* x_st = (const float*)d_in[0];
    const int*   ei_st = (const int*)d_in[1];
    const float* x_sc = (const float*)d_in[2];
    const int*   ei_sc = (const int*)d_in[3];
    const int N = in_sizes[0] / FDIM;
    const int E = in_sizes[1] / 2;
    const int Etot = E + N;

    float* out = (float*)d_out;
    float* beta_st = out + FDIM;
    float* beta_sc = beta_st + N;

    const size_t NF = (size_t)N * HC;
    float* ws = (float*)d_ws;
    float* h_buf  = ws;                      // NF floats (later reused as hid: N*128)
    float* og_buf = h_buf + NF;              // NF
    float* e_buf  = og_buf + NF;             // Etot*3
    float* ssrc   = e_buf + (size_t)Etot * HEADS;
    float* sdst   = ssrc + (size_t)N * HEADS;
    float* mbuf   = sdst + (size_t)N * HEADS;
    float* dnm    = mbuf + (size_t)N * HEADS;
    float* zst    = dnm + (size_t)N * HEADS;
    float* zsc    = zst + FDIM;

    for (int tag = 0; tag < 2; ++tag) {
        const float* x  = tag ? x_sc : x_st;
        const int*   ei = tag ? ei_sc : ei_st;
        const float* wg   = (const float*)d_in[tag ? 12 : 4];
        const float* asrc = (const float*)d_in[tag ? 13 : 5];
        const float* adst = (const float*)d_in[tag ? 14 : 6];
        const float* bg   = (const float*)d_in[tag ? 15 : 7];
        const float* w1   = (const float*)d_in[tag ? 16 : 8];
        const float* b1   = (const float*)d_in[tag ? 17 : 9];
        const float* w2   = (const float*)d_in[tag ? 18 : 10];
        const float* b2   = (const float*)d_in[tag ? 19 : 11];
        float* beta = tag ? beta_sc : beta_st;
        float* z    = tag ? zsc : zst;

        dim3 g1((N + 63) / 64, HC / 64);
        gemm_tile<<<g1, 256, 0, stream>>>(x, wg, h_buf, N, FDIM, HC);

        attn_scores<<<(N + 3) / 4, 256, 0, stream>>>(h_buf, asrc, adst, ssrc, sdst, N);

        hipMemsetAsync(mbuf, 0xFF, (size_t)N * HEADS * 4, stream);
        hipMemsetAsync(dnm, 0, (size_t)N * HEADS * 4, stream);
        hipMemsetAsync(og_buf, 0, NF * 4, stream);

        int ethreads = Etot * HEADS;
        edge_pass1<<<(ethreads + 255) / 256, 256, 0, stream>>>(ei, ssrc, sdst, e_buf, mbuf, E, Etot);
        edge_pass2<<<(ethreads + 255) / 256, 256, 0, stream>>>(ei, mbuf, e_buf, dnm, E, Etot);
        size_t p3threads = (size_t)ethreads * 64;
        edge_pass3<<<(unsigned)((p3threads + 255) / 256), 256, 0, stream>>>(ei, e_buf, dnm, h_buf, og_buf, E, Etot);

        bias_elu<<<((int)NF + 255) / 256, 256, 0, stream>>>(og_buf, bg, (int)NF);

        dim3 g2((N + 63) / 64, HIDDIM / 64);
        gemm_tile<<<g2, 256, 0, stream>>>(og_buf, w1, h_buf, N, HC, HIDDIM);  // hid aliases h_buf

        beta_kernel<<<(N + 3) / 4, 256, 0, stream>>>(h_buf, b1, w2, b2, beta, N);

        hipMemsetAsync(z, 0, FDIM * 4, stream);
        xt_beta<<<512, 256, 0, stream>>>(x, beta, z, N);
    }
    final_sigmoid<<<1, FDIM, 0, stream>>>(zst, zsc, out);
}

// Round 2
// 904.884 us; speedup vs baseline: 1.9474x; 1.9474x over previous
//
#include <hip/hip_runtime.h>
#include <math.h>

#define HEADS 3
#define CDIM 64
#define FDIM 256
#define HC 192      // HEADS*CDIM
#define HIDDIM 128
#define NEG 0.2f

#define SCAN_BLK 256
#define SCAN_ELEMS 1024  // 4 per thread

// ---------------- GEMM (f32, 64x64 tile) ----------------
// C[M,N] = A[M,K] @ B[K,N];  requires K%32==0, N%64==0. Row guards on M.
__global__ __launch_bounds__(256) void gemm_tile(const float* __restrict__ A,
                                                 const float* __restrict__ B,
                                                 float* __restrict__ C,
                                                 int M, int K, int N) {
    __shared__ __align__(16) float AsT[32][68];
    __shared__ __align__(16) float Bs[32][68];
    const int tid = threadIdx.x;
    const int tx = tid & 15, ty = tid >> 4;
    const int row0 = blockIdx.x * 64, col0 = blockIdx.y * 64;
    float acc[4][4] = {};
    for (int k0 = 0; k0 < K; k0 += 32) {
        #pragma unroll
        for (int p = 0; p < 2; ++p) {
            int rr = (tid >> 3) + p * 32;
            int k4 = (tid & 7) * 4;
            int gr = row0 + rr;
            float4 v = make_float4(0.f, 0.f, 0.f, 0.f);
            if (gr < M) v = *(const float4*)(A + (size_t)gr * K + k0 + k4);
            AsT[k4 + 0][rr] = v.x; AsT[k4 + 1][rr] = v.y;
            AsT[k4 + 2][rr] = v.z; AsT[k4 + 3][rr] = v.w;
        }
        #pragma unroll
        for (int p = 0; p < 2; ++p) {
            int kr = (tid >> 4) + p * 16;
            int c4 = (tid & 15) * 4;
            float4 v = *(const float4*)(B + (size_t)(k0 + kr) * N + col0 + c4);
            Bs[kr][c4 + 0] = v.x; Bs[kr][c4 + 1] = v.y;
            Bs[kr][c4 + 2] = v.z; Bs[kr][c4 + 3] = v.w;
        }
        __syncthreads();
        #pragma unroll
        for (int kk = 0; kk < 32; ++kk) {
            float4 a4 = *(const float4*)&AsT[kk][ty * 4];
            float4 b4 = *(const float4*)&Bs[kk][tx * 4];
            float av[4] = {a4.x, a4.y, a4.z, a4.w};
            float bv[4] = {b4.x, b4.y, b4.z, b4.w};
            #pragma unroll
            for (int i = 0; i < 4; ++i)
                #pragma unroll
                for (int j = 0; j < 4; ++j)
                    acc[i][j] = fmaf(av[i], bv[j], acc[i][j]);
        }
        __syncthreads();
    }
    #pragma unroll
    for (int i = 0; i < 4; ++i) {
        int gr = row0 + ty * 4 + i;
        if (gr < M) {
            float4 v = make_float4(acc[i][0], acc[i][1], acc[i][2], acc[i][3]);
            *(float4*)(C + (size_t)gr * N + col0 + tx * 4) = v;
        }
    }
}

// ---------------- attention scores ----------------
__global__ __launch_bounds__(256) void attn_scores(const float* __restrict__ Hm,
                                                   const float* __restrict__ a_src,
                                                   const float* __restrict__ a_dst,
                                                   float* __restrict__ s_src,
                                                   float* __restrict__ s_dst, int N) {
    int wave = (int)((blockIdx.x * (size_t)blockDim.x + threadIdx.x) >> 6);
    int lane = threadIdx.x & 63;
    if (wave >= N) return;
    #pragma unroll
    for (int head = 0; head < HEADS; ++head) {
        float v = Hm[(size_t)wave * HC + head * CDIM + lane];
        float ps = v * a_src[head * CDIM + lane];
        float pd = v * a_dst[head * CDIM + lane];
        #pragma unroll
        for (int off = 32; off; off >>= 1) {
            ps += __shfl_down(ps, off);
            pd += __shfl_down(pd, off);
        }
        if (lane == 0) {
            s_src[wave * HEADS + head] = ps;
            s_dst[wave * HEADS + head] = pd;
        }
    }
}

// ---------------- CSR build ----------------
__global__ __launch_bounds__(256) void deg_count(const int* __restrict__ ei,
                                                 int* __restrict__ deg, int E, int Etot) {
    int e = blockIdx.x * blockDim.x + threadIdx.x;
    if (e >= Etot) return;
    int dst = (e < E) ? ei[E + e] : (e - E);
    atomicAdd(&deg[dst], 1);
}

// per-block exclusive scan (1024 elems/block), emits block sums
__global__ __launch_bounds__(SCAN_BLK) void scan1(const int* __restrict__ deg,
                                                  int* __restrict__ row_ptr,
                                                  int* __restrict__ bsums, int N) {
    __shared__ int sm[SCAN_BLK];
    int tid = threadIdx.x;
    int base = blockIdx.x * SCAN_ELEMS + tid * 4;
    int v[4];
    #pragma unroll
    for (int j = 0; j < 4; ++j) v[j] = (base + j < N) ? deg[base + j] : 0;
    int tsum = v[0] + v[1] + v[2] + v[3];
    sm[tid] = tsum;
    __syncthreads();
    for (int off = 1; off < SCAN_BLK; off <<= 1) {
        int y = (tid >= off) ? sm[tid - off] : 0;
        __syncthreads();
        sm[tid] += y;
        __syncthreads();
    }
    int excl = sm[tid] - tsum;
    int run = excl;
    #pragma unroll
    for (int j = 0; j < 4; ++j) {
        if (base + j < N) row_ptr[base + j] = run;
        run += v[j];
    }
    if (tid == SCAN_BLK - 1) bsums[blockIdx.x] = sm[SCAN_BLK - 1];
}

// exclusive scan of block sums (single block, nb <= 256)
__global__ __launch_bounds__(SCAN_BLK) void scan2(int* __restrict__ bsums, int nb) {
    __shared__ int sm[SCAN_BLK];
    int tid = threadIdx.x;
    int v = (tid < nb) ? bsums[tid] : 0;
    sm[tid] = v;
    __syncthreads();
    for (int off = 1; off < SCAN_BLK; off <<= 1) {
        int y = (tid >= off) ? sm[tid - off] : 0;
        __syncthreads();
        sm[tid] += y;
        __syncthreads();
    }
    if (tid < nb) bsums[tid] = sm[tid] - v;
}

__global__ __launch_bounds__(256) void scan_fixup(int* __restrict__ row_ptr,
                                                  int* __restrict__ cursor,
                                                  const int* __restrict__ bsums, int N) {
    int i = blockIdx.x * blockDim.x + threadIdx.x;
    if (i >= N) return;
    int r = row_ptr[i] + bsums[i / SCAN_ELEMS];
    row_ptr[i] = r;
    cursor[i] = r;
}

__global__ __launch_bounds__(256) void scatter_edges(const int* __restrict__ ei,
                                                     int* __restrict__ cursor,
                                                     int* __restrict__ csr_src,
                                                     int E, int Etot) {
    int e = blockIdx.x * blockDim.x + threadIdx.x;
    if (e >= Etot) return;
    int src, dst;
    if (e < E) { src = ei[e]; dst = ei[E + e]; } else { src = dst = e - E; }
    int pos = atomicAdd(&cursor[dst], 1);
    csr_src[pos] = src;
}

// ---------------- fused softmax + aggregation + bias + ELU ----------------
// one wave per dst node; lane = channel; 3 heads held in registers
__global__ __launch_bounds__(256) void csr_agg(const int* __restrict__ row_ptr,
                                               const int* __restrict__ deg,
                                               const int* __restrict__ csr_src,
                                               const float* __restrict__ s_src,
                                               const float* __restrict__ s_dst,
                                               const float* __restrict__ Hm,
                                               const float* __restrict__ bias,
                                               float* __restrict__ outg, int N) {
    int gid = blockIdx.x * blockDim.x + threadIdx.x;
    int node = gid >> 6, lane = gid & 63;
    if (node >= N) return;
    int start = row_ptr[node];
    int cnt = deg[node];
    float sd0 = s_dst[node * 3 + 0];
    float sd1 = s_dst[node * 3 + 1];
    float sd2 = s_dst[node * 3 + 2];
    // pass A: per-head max (redundant across lanes, cheap scalar work)
    float m0 = -1e30f, m1 = -1e30f, m2 = -1e30f;
    for (int i = 0; i < cnt; ++i) {
        int s = __builtin_amdgcn_readfirstlane(csr_src[start + i]);
        float a0 = s_src[s * 3 + 0] + sd0; a0 = a0 >= 0.f ? a0 : NEG * a0;
        float a1 = s_src[s * 3 + 1] + sd1; a1 = a1 >= 0.f ? a1 : NEG * a1;
        float a2 = s_src[s * 3 + 2] + sd2; a2 = a2 >= 0.f ? a2 : NEG * a2;
        m0 = fmaxf(m0, a0); m1 = fmaxf(m1, a1); m2 = fmaxf(m2, a2);
    }
    // pass B: accumulate numerator and denominator
    float acc0 = 0.f, acc1 = 0.f, acc2 = 0.f;
    float d0 = 0.f, d1 = 0.f, d2 = 0.f;
    for (int i = 0; i < cnt; ++i) {
        int s = __builtin_amdgcn_readfirstlane(csr_src[start + i]);
        float a0 = s_src[s * 3 + 0] + sd0; a0 = a0 >= 0.f ? a0 : NEG * a0;
        float a1 = s_src[s * 3 + 1] + sd1; a1 = a1 >= 0.f ? a1 : NEG * a1;
        float a2 = s_src[s * 3 + 2] + sd2; a2 = a2 >= 0.f ? a2 : NEG * a2;
        float p0 = __expf(a0 - m0);
        float p1 = __expf(a1 - m1);
        float p2 = __expf(a2 - m2);
        d0 += p0; d1 += p1; d2 += p2;
        const float* hrow = Hm + (size_t)s * HC + lane;
        acc0 = fmaf(p0, hrow[0], acc0);
        acc1 = fmaf(p1, hrow[64], acc1);
        acc2 = fmaf(p2, hrow[128], acc2);
    }
    float o0 = acc0 / (d0 + 1e-16f) + bias[lane];
    float o1 = acc1 / (d1 + 1e-16f) + bias[64 + lane];
    float o2 = acc2 / (d2 + 1e-16f) + bias[128 + lane];
    o0 = o0 > 0.f ? o0 : expm1f(o0);
    o1 = o1 > 0.f ? o1 : expm1f(o1);
    o2 = o2 > 0.f ? o2 : expm1f(o2);
    float* orow = outg + (size_t)node * HC + lane;
    orow[0] = o0; orow[64] = o1; orow[128] = o2;
}

// ---------------- MLP tail ----------------
__global__ __launch_bounds__(256) void beta_kernel(const float* __restrict__ hid,
                                                   const float* __restrict__ b1,
                                                   const float* __restrict__ w2,
                                                   const float* __restrict__ b2,
                                                   float* __restrict__ beta, int N) {
    int gid = blockIdx.x * blockDim.x + threadIdx.x;
    int row = gid >> 6, lane = gid & 63;
    if (row >= N) return;
    float acc = 0.f;
    #pragma unroll
    for (int half = 0; half < 2; ++half) {
        int j = half * 64 + lane;
        float v = hid[(size_t)row * HIDDIM + j] + b1[j];
        float g = 0.5f * v * (1.f + erff(v * 0.70710678118654752f));
        acc += g * w2[j];
    }
    #pragma unroll
    for (int off = 32; off; off >>= 1) acc += __shfl_down(acc, off);
    if (lane == 0) beta[row] = (acc + b2[0]) * 0.01f;
}

__global__ __launch_bounds__(256) void xt_beta(const float* __restrict__ X,
                                               const float* __restrict__ beta,
                                               float* __restrict__ z, int N) {
    int f = threadIdx.x;  // 256
    int nPer = (N + gridDim.x - 1) / gridDim.x;
    int n0 = blockIdx.x * nPer;
    int n1 = min(n0 + nPer, N);
    float acc = 0.f;
    for (int n = n0; n < n1; ++n)
        acc = fmaf(X[(size_t)n * FDIM + f], beta[n], acc);
    atomicAdd(&z[f], acc);
}

__global__ void final_sigmoid(const float* __restrict__ zst,
                              const float* __restrict__ zsc,
                              float* __restrict__ out) {
    int f = threadIdx.x;
    float v = zsc[f] + 0.5f * zst[f];
    out[f] = 1.f / (1.f + expf(-v));
}

extern "C" void kernel_launch(void* const* d_in, const int* in_sizes, int n_in,
                              void* d_out, int out_size, void* d_ws, size_t ws_size,
                              hipStream_t stream) {
    const float* x_st = (const float*)d_in[0];
    const int*   ei_st = (const int*)d_in[1];
    const float* x_sc = (const float*)d_in[2];
    const int*   ei_sc = (const int*)d_in[3];
    const int N = in_sizes[0] / FDIM;
    const int E = in_sizes[1] / 2;
    const int Etot = E + N;

    float* out = (float*)d_out;
    float* beta_st = out + FDIM;
    float* beta_sc = beta_st + N;

    const size_t NF = (size_t)N * HC;
    float* ws = (float*)d_ws;
    float* h_buf  = ws;                               // NF (reused for hid N*128)
    float* og_buf = h_buf + NF;                       // NF
    float* ssrc   = og_buf + NF;                      // 3N
    float* sdst   = ssrc + (size_t)N * HEADS;         // 3N
    float* zst    = sdst + (size_t)N * HEADS;         // 256
    float* zsc    = zst + FDIM;                       // 256
    int* iw       = (int*)(zsc + FDIM);
    int* row_ptr  = iw;                               // N
    int* degb     = row_ptr + N;                      // N
    int* cursor   = degb + N;                         // N
    int* bsums    = cursor + N;                       // 256
    int* csr_src  = bsums + 256;                      // Etot

    const int nb_scan = (N + SCAN_ELEMS - 1) / SCAN_ELEMS;

    for (int tag = 0; tag < 2; ++tag) {
        const float* x  = tag ? x_sc : x_st;
        const int*   ei = tag ? ei_sc : ei_st;
        const float* wg   = (const float*)d_in[tag ? 12 : 4];
        const float* asrc = (const float*)d_in[tag ? 13 : 5];
        const float* adst = (const float*)d_in[tag ? 14 : 6];
        const float* bg   = (const float*)d_in[tag ? 15 : 7];
        const float* w1   = (const float*)d_in[tag ? 16 : 8];
        const float* b1   = (const float*)d_in[tag ? 17 : 9];
        const float* w2   = (const float*)d_in[tag ? 18 : 10];
        const float* b2   = (const float*)d_in[tag ? 19 : 11];
        float* beta = tag ? beta_sc : beta_st;
        float* z    = tag ? zsc : zst;

        // h = x @ W
        dim3 g1((N + 63) / 64, HC / 64);
        gemm_tile<<<g1, 256, 0, stream>>>(x, wg, h_buf, N, FDIM, HC);

        attn_scores<<<(N + 3) / 4, 256, 0, stream>>>(h_buf, asrc, adst, ssrc, sdst, N);

        // CSR build (overlaps GEMM-dependency-free part conceptually; sequential on stream)
        hipMemsetAsync(degb, 0, (size_t)N * 4, stream);
        deg_count<<<(Etot + 255) / 256, 256, 0, stream>>>(ei, degb, E, Etot);
        scan1<<<nb_scan, SCAN_BLK, 0, stream>>>(degb, row_ptr, bsums, N);
        scan2<<<1, SCAN_BLK, 0, stream>>>(bsums, nb_scan);
        scan_fixup<<<(N + 255) / 256, 256, 0, stream>>>(row_ptr, cursor, bsums, N);
        scatter_edges<<<(Etot + 255) / 256, 256, 0, stream>>>(ei, cursor, csr_src, E, Etot);

        // fused softmax+aggregate+bias+elu
        csr_agg<<<(N + 3) / 4, 256, 0, stream>>>(row_ptr, degb, csr_src, ssrc, sdst,
                                                 h_buf, bg, og_buf, N);

        // hid = og @ w1
        dim3 g2((N + 63) / 64, HIDDIM / 64);
        gemm_tile<<<g2, 256, 0, stream>>>(og_buf, w1, h_buf, N, HC, HIDDIM);

        beta_kernel<<<(N + 3) / 4, 256, 0, stream>>>(h_buf, b1, w2, b2, beta, N);

        hipMemsetAsync(z, 0, FDIM * 4, stream);
        xt_beta<<<512, 256, 0, stream>>>(x, beta, z, N);
    }
    final_sigmoid<<<1, FDIM, 0, stream>>>(zst, zsc, out);
}